// Round 10
// baseline (8686.412 us; speedup 1.0000x reference)
//
#include <hip/hip_runtime.h>
#include <hip/hip_bf16.h>

#define TSTEPS 512
#define BATCH  32
#define NIN    512
#define NH     1024
#define BNH    (BATCH * NH)   // 32768

typedef __attribute__((ext_vector_type(8))) short  short8v;
typedef __attribute__((ext_vector_type(4))) float  float4v;
typedef unsigned long long ull;

__device__ __forceinline__ unsigned short f2bf(float f) {
  return __builtin_bit_cast(unsigned short, __float2bfloat16(f));
}
__device__ __forceinline__ float4v mfma16(short8v a, short8v b, float4v c) {
  return __builtin_amdgcn_mfma_f32_16x16x32_bf16(a, b, c, 0, 0, 0);
}

// bf16 fragment layout (R8-verified): element (b,k) at
//   (k>>5)*1024 + (b>>4)*512 + (((b&15)|(((k>>3)&3)<<4))<<3) + (k&7)
// -> wave A-fragment: 16B at base + q*1024 + mt*512 + lane*8.
__device__ __forceinline__ int swzx(int b, int k) {
  return (k >> 5) * 1024 + (b >> 4) * 512 +
         (((b & 15) | (((k >> 3) & 3) << 4)) << 3) + (k & 7);
}

__device__ __forceinline__ short8v cvt8(float4 f0, float4 f1) {
  short8v r;
  r[0] = (short)f2bf(f0.x); r[1] = (short)f2bf(f0.y);
  r[2] = (short)f2bf(f0.z); r[3] = (short)f2bf(f0.w);
  r[4] = (short)f2bf(f1.x); r[5] = (short)f2bf(f1.y);
  r[6] = (short)f2bf(f1.z); r[7] = (short)f2bf(f1.w);
  return r;
}

// 16 fragments (16B each) via COMPILER-MANAGED scoped 8B-pair loads (R7-proven
// safe: no async-asm register hazards; compiler sinks one waitcnt before use).
__device__ __forceinline__ void kload_b(const ushort* __restrict__ base, int lane,
                                        short8v (&f)[2][8]) {
#pragma unroll
  for (int mt = 0; mt < 2; ++mt)
#pragma unroll
    for (int q = 0; q < 8; ++q) {
      const ull* p = (const ull*)(base + q * 1024 + mt * 512 + lane * 8);
      ull lo = __hip_atomic_load(p,     __ATOMIC_RELAXED, __HIP_MEMORY_SCOPE_SYSTEM);
      ull hi = __hip_atomic_load(p + 1, __ATOMIC_RELAXED, __HIP_MEMORY_SCOPE_SYSTEM);
      union { ull u[2]; short8v v; } cv;
      cv.u[0] = lo; cv.u[1] = hi;
      f[mt][q] = cv.v;
    }
}

// plain cached 16B loads (immutable xbf)
__device__ __forceinline__ void kloadp(const ushort* __restrict__ base, int lane,
                                       short8v (&f)[2][8]) {
#pragma unroll
  for (int mt = 0; mt < 2; ++mt)
#pragma unroll
    for (int q = 0; q < 8; ++q)
      f[mt][q] = *(const short8v*)(base + q * 1024 + mt * 512 + lane * 8);
}

__device__ __forceinline__ void kmfma(const short8v (&f)[2][8],
                                      const short8v (&w)[8][2],
                                      float4v (&acc)[2][2]) {
#pragma unroll
  for (int q = 0; q < 8; ++q)
#pragma unroll
    for (int mt = 0; mt < 2; ++mt) {
      acc[mt][0] = mfma16(f[mt][q], w[q][0], acc[mt][0]);
      acc[mt][1] = mfma16(f[mt][q], w[q][1], acc[mt][1]);
    }
}

// wave-parallel flag poll: PL flag slots per lane, spin until all >= need
template<int PL>
__device__ __forceinline__ void wpoll(const int* __restrict__ flags, int base,
                                      int need, int lane) {
  if (need <= 0) return;
  const int* p0 = &flags[(size_t)(base + lane * PL) * 16];
  for (;;) {
    int mn = 0x7fffffff;
#pragma unroll
    for (int j = 0; j < PL; ++j) {
      int v = __hip_atomic_load(p0 + j * 16, __ATOMIC_RELAXED, __HIP_MEMORY_SCOPE_SYSTEM);
      mn = v < mn ? v : mn;
    }
    if (__all(mn >= need)) break;
    __builtin_amdgcn_s_sleep(1);
  }
  asm volatile("" ::: "memory");
}

// Persistent kernel: 256 WGs x 512 threads (8 waves), 1 WG/CU.
// Layer by XCD residue; rank 0..127; WG owns 8 h-cols. Weights in VGPRs.
// Wave roles: wv0-3 = epilogue + slack loads; wv4-7 = tight-chain consumers
// (poll+load overlapped with the epilogue). Per-epilogue-WAVE flags (wave
// drain -> lane0 fire). ONE raw s_barrier per step (zl triple-buffered).
//   L0: wv0,1 x (plain); wv4-7 h0 tight (ring0); wv0-3 backpressure poll.
//   L1: wv0-3 h0 slack (ring0); wv4-7 h1 tight (ring1). All h loads scoped.
__global__ __launch_bounds__(512, 2)
void lstm_v10(const ushort* __restrict__ xbf,
              const float* __restrict__ c0_in,
              const float* __restrict__ W0, const float* __restrict__ b0_,
              const float* __restrict__ W1, const float* __restrict__ b1_,
              ushort* __restrict__ ring0,   // [8][BNH] bf16, fragment layout
              ushort* __restrict__ ring1,   // [2][BNH] bf16, fragment layout
              int* __restrict__ flags,      // 1024 wave-flags x 16 ints
              float* __restrict__ out) {
  __shared__ float zl[3][8][32][36];        // triple-buffered z partials

  const int wg    = blockIdx.x;
  const int tid   = threadIdx.x;
  const int res   = wg & 7;
  const int layer = res >> 2;
  const int rank  = (wg >> 3) * 4 + (res & 3);
  const int j0    = rank * 8;
  const int K     = layer ? (2 * NH) : (NIN + NH);
  const float* W    = layer ? W1 : W0;
  const float* bias = layer ? b1_ : b0_;

  const int wv = tid >> 6, lane = tid & 63;
  const int kslot = layer ? wv : (wv < 2 ? wv : wv - 2);   // L0: wv2,3 idle
  const bool kact = layer || wv < 2 || wv >= 4;

  // ---- weight K-slice into registers (once) ----
  short8v wreg[8][2];
  if (kact) {
    const int wkbase = kslot * 256;
#pragma unroll
    for (int q = 0; q < 8; ++q)
#pragma unroll
      for (int nt = 0; nt < 2; ++nt) {
        int n  = nt * 16 + (lane & 15);
        int gr = (n >> 3) * NH + j0 + (n & 7);
        int k  = wkbase + q * 32 + (lane >> 4) * 8;
        const float* p = W + (size_t)gr * K + k;
        wreg[q][nt] = cvt8(*(const float4*)p, *(const float4*)(p + 4));
      }
  } else {
#pragma unroll
    for (int q = 0; q < 8; ++q) { wreg[q][0] = short8v{}; wreg[q][1] = short8v{}; }
  }

  // zero all 3 zl buffers for my wave slice
  for (int b3 = 0; b3 < 3; ++b3)
    for (int i = lane; i < 32 * 36; i += 64) (&zl[b3][wv][0][0])[i] = 0.f;

  // epilogue state (threads 0..255): thread -> (batch bb, col jj)
  const int bb = tid >> 3, jj = tid & 7;
  float c = 0.f, bg0 = 0.f, bg1 = 0.f, bg2 = 0.f, bg3 = 0.f;
  if (tid < 256) {
    bg0 = bias[0 * NH + j0 + jj];
    bg1 = bias[1 * NH + j0 + jj];
    bg2 = bias[2 * NH + j0 + jj];
    bg3 = bias[3 * NH + j0 + jj];
    c   = c0_in[layer * BNH + bb * NH + j0 + jj];
  }

  __syncthreads();

  for (int it = 0; it <= TSTEPS; ++it) {
    const bool gemm = (it < TSTEPS);
    short8v f[2][8];

    // ---- tight waves: poll own-layer wave-flags, issue scoped loads ----
    if (gemm && wv >= 4) {
      const int i = wv - 4;
      if (layer == 0) {
        wpoll<2>(flags, 128 * i, it, lane);               // L0 ranks [32i,32i+32)
        kload_b(ring0 + (size_t)(it & 7) * BNH + 8 * i * 1024, lane, f);
      } else {
        wpoll<2>(flags, 512 + 128 * i, it, lane);         // L1 ranks [32i,32i+32)
        kload_b(ring1 + (size_t)((it + 1) & 1) * BNH + 8 * i * 1024, lane, f);
      }
    }
    // ---- L0 epilogue waves: backpressure BEFORE the ring0 overwrite ----
    if (layer == 0 && wv < 4) {
      wpoll<2>(flags, 512 + 128 * wv, it - 6, lane);      // L1 done it-7 (+margin)
    }
    // ---- epilogue for step it-1 (waves 0-3) ----
    if (it >= 1 && tid < 256) {
      const int zb = (it + 2) % 3;                        // (it-1) mod 3
      float zg[4];
#pragma unroll
      for (int g = 0; g < 4; ++g) {
        float s = 0.f;
#pragma unroll
        for (int w = 0; w < 8; ++w) s += zl[zb][w][bb][g * 8 + jj];
        zg[g] = s;
      }
      float g1 = 1.f / (1.f + __expf(-(zg[0] + bg0)));
      float g2 = 1.f / (1.f + __expf(-(zg[1] + bg1)));
      float g3 = 1.f / (1.f + __expf(-(zg[2] + bg2)));
      float o  = tanhf(zg[3] + bg3);
      c = c * g1 + o * g2;
      float h = tanhf(c) * g3;
      unsigned short hb = f2bf(h);
      int so = swzx(bb, j0 + jj);
      if (layer == 0) {
        __hip_atomic_store(&ring0[(size_t)(it & 7) * BNH + so], hb,
                           __ATOMIC_RELAXED, __HIP_MEMORY_SCOPE_SYSTEM);
      } else {
        __hip_atomic_store(&ring1[(size_t)((it + 1) & 1) * BNH + so], hb,
                           __ATOMIC_RELAXED, __HIP_MEMORY_SCOPE_SYSTEM);
      }
      // wave-local drain (scoped store ack == visible at LLC), then wave flag
      asm volatile("s_waitcnt vmcnt(0)" ::: "memory");
      if (lane == 0) {
        __hip_atomic_store(&flags[(size_t)((layer * 128 + rank) * 4 + wv) * 16], it,
                           __ATOMIC_RELAXED, __HIP_MEMORY_SCOPE_SYSTEM);
      }
      if (layer == 1)
        out[(size_t)(it - 1) * BNH + bb * NH + j0 + jj] = h;   // plain, post-flag
    }
    // ---- slack loads (epilogue waves, after flag fire) ----
    if (gemm && wv < 4) {
      if (layer == 0) {
        if (wv < 2) kloadp(xbf + (size_t)it * 16384 + 8 * wv * 1024, lane, f);
      } else {
        wpoll<2>(flags, 128 * wv, it + 1, lane);          // L0 done step it
        kload_b(ring0 + (size_t)((it + 1) & 7) * BNH + 8 * wv * 1024, lane, f);
      }
    }
    // ---- compute + zl publish ----
    if (gemm && kact) {
      float4v acc[2][2] = {{{0,0,0,0},{0,0,0,0}},{{0,0,0,0},{0,0,0,0}}};
      kmfma(f, wreg, acc);
      const int zc = it % 3;
#pragma unroll
      for (int mt = 0; mt < 2; ++mt)
#pragma unroll
        for (int nt = 0; nt < 2; ++nt)
#pragma unroll
          for (int r = 0; r < 4; ++r)
            zl[zc][wv][mt * 16 + (lane >> 4) * 4 + r][nt * 16 + (lane & 15)] = acc[mt][nt][r];
    }
    // single barrier per step: LDS drained, global loads may stay in flight
    asm volatile("s_waitcnt lgkmcnt(0)" ::: "memory");
    __builtin_amdgcn_s_barrier();
    asm volatile("" ::: "memory");
  }
}

// prep: x -> bf16 fragment layout, ring init slots, zero flags, output tail
__global__ void prep(const float* __restrict__ x,
                     const float* __restrict__ h0_in, const float* __restrict__ c0_in,
                     ushort* __restrict__ xbf, ushort* __restrict__ ring0,
                     ushort* __restrict__ ring1, int* __restrict__ flags,
                     float* __restrict__ out) {
  int i = blockIdx.x * blockDim.x + threadIdx.x;   // 0 .. T*B*NIN-1
  {
    int t = i >> 14, rem = i & 16383;
    int b = rem >> 9, k = rem & 511;
    xbf[(size_t)t * 16384 + swzx(b, k)] = f2bf(x[i]);
  }
  if (i < BNH) {
    int b = i >> 10, j = i & 1023;
    int so = swzx(b, j);
    __hip_atomic_store(&ring0[so], f2bf(h0_in[i]),              // slot 0 = h0_{-1}
                       __ATOMIC_RELAXED, __HIP_MEMORY_SCOPE_SYSTEM);
    __hip_atomic_store(&ring1[BNH + so], f2bf(h0_in[BNH + i]),  // slot 1 = h1_{-1}
                       __ATOMIC_RELAXED, __HIP_MEMORY_SCOPE_SYSTEM);
  }
  if (i < 1024 * 16) {
    __hip_atomic_store(&flags[i], 0, __ATOMIC_RELAXED, __HIP_MEMORY_SCOPE_SYSTEM);
  }
  if (i < 2 * BNH) {
    const size_t TB = (size_t)TSTEPS * BNH;
    out[TB + i]           = h0_in[i];
    out[TB + 2 * BNH + i] = c0_in[i];
  }
}

extern "C" void kernel_launch(void* const* d_in, const int* in_sizes, int n_in,
                              void* d_out, int out_size, void* d_ws, size_t ws_size,
                              hipStream_t stream) {
  const float* x  = (const float*)d_in[0];
  const float* h0 = (const float*)d_in[1];
  const float* c0 = (const float*)d_in[2];
  const float* W0 = (const float*)d_in[3];
  const float* b0 = (const float*)d_in[4];
  const float* W1 = (const float*)d_in[5];
  const float* b1 = (const float*)d_in[6];
  float* out = (float*)d_out;

  ushort* xbf   = (ushort*)d_ws;                              // 16 MiB
  ushort* ring0 = (ushort*)((char*)d_ws + 16777216);          // 512 KiB
  ushort* ring1 = (ushort*)((char*)d_ws + 17301504);          // 128 KiB
  int*    flags = (int*)((char*)d_ws + 17432576);             // 64 KiB

  prep<<<dim3(32768), dim3(256), 0, stream>>>(x, h0, c0, xbf, ring0, ring1, flags, out);

  void* args[] = {(void*)&xbf, (void*)&c0, (void*)&W0, (void*)&b0, (void*)&W1,
                  (void*)&b1, (void*)&ring0, (void*)&ring1, (void*)&flags, (void*)&out};
  (void)hipLaunchCooperativeKernel((const void*)lstm_v10, dim3(256), dim3(512),
                                   args, 0, stream);
}

// Round 11
// 8678.442 us; speedup vs baseline: 1.0009x; 1.0009x over previous
//
#include <hip/hip_runtime.h>
#include <hip/hip_bf16.h>

#define TSTEPS 512
#define BATCH  32
#define NIN    512
#define NH     1024
#define BNH    (BATCH * NH)   // 32768

typedef __attribute__((ext_vector_type(8))) short  short8v;
typedef __attribute__((ext_vector_type(4))) float  float4v;
typedef unsigned long long ull;

__device__ __forceinline__ unsigned short f2bf(float f) {
  return __builtin_bit_cast(unsigned short, __float2bfloat16(f));
}
__device__ __forceinline__ float4v mfma16(short8v a, short8v b, float4v c) {
  return __builtin_amdgcn_mfma_f32_16x16x32_bf16(a, b, c, 0, 0, 0);
}

// bf16 fragment layout (R8-verified): element (b,k) at
//   (k>>5)*1024 + (b>>4)*512 + (((b&15)|(((k>>3)&3)<<4))<<3) + (k&7)
// -> wave A-fragment: 16B at base + q*1024 + mt*512 + lane*8.
__device__ __forceinline__ int swzx(int b, int k) {
  return (k >> 5) * 1024 + (b >> 4) * 512 +
         (((b & 15) | (((k >> 3) & 3) << 4)) << 3) + (k & 7);
}

__device__ __forceinline__ short8v cvt8(float4 f0, float4 f1) {
  short8v r;
  r[0] = (short)f2bf(f0.x); r[1] = (short)f2bf(f0.y);
  r[2] = (short)f2bf(f0.z); r[3] = (short)f2bf(f0.w);
  r[4] = (short)f2bf(f1.x); r[5] = (short)f2bf(f1.y);
  r[6] = (short)f2bf(f1.z); r[7] = (short)f2bf(f1.w);
  return r;
}

// 16 fragments (16B each) via COMPILER-MANAGED scoped 8B-pair loads (R7-proven
// safe: no async-asm register hazards; compiler sinks waitcnts before use).
__device__ __forceinline__ void kload_b(const ushort* __restrict__ base, int lane,
                                        short8v (&f)[2][8]) {
#pragma unroll
  for (int mt = 0; mt < 2; ++mt)
#pragma unroll
    for (int q = 0; q < 8; ++q) {
      const ull* p = (const ull*)(base + q * 1024 + mt * 512 + lane * 8);
      ull lo = __hip_atomic_load(p,     __ATOMIC_RELAXED, __HIP_MEMORY_SCOPE_SYSTEM);
      ull hi = __hip_atomic_load(p + 1, __ATOMIC_RELAXED, __HIP_MEMORY_SCOPE_SYSTEM);
      union { ull u[2]; short8v v; } cv;
      cv.u[0] = lo; cv.u[1] = hi;
      f[mt][q] = cv.v;
    }
}

// plain cached 16B loads (immutable xbf)
__device__ __forceinline__ void kloadp(const ushort* __restrict__ base, int lane,
                                       short8v (&f)[2][8]) {
#pragma unroll
  for (int mt = 0; mt < 2; ++mt)
#pragma unroll
    for (int q = 0; q < 8; ++q)
      f[mt][q] = *(const short8v*)(base + q * 1024 + mt * 512 + lane * 8);
}

__device__ __forceinline__ void kmfma(const short8v (&f)[2][8],
                                      const short8v (&w)[8][2],
                                      float4v (&acc)[2][2]) {
#pragma unroll
  for (int q = 0; q < 8; ++q)
#pragma unroll
    for (int mt = 0; mt < 2; ++mt) {
      acc[mt][0] = mfma16(f[mt][q], w[q][0], acc[mt][0]);
      acc[mt][1] = mfma16(f[mt][q], w[q][1], acc[mt][1]);
    }
}

// wave-parallel flag poll: PL flag slots per lane, spin until all >= need
template<int PL>
__device__ __forceinline__ void wpoll(const int* __restrict__ flags, int base,
                                      int need, int lane) {
  if (need <= 0) return;
  const int* p0 = &flags[(size_t)(base + lane * PL) * 16];
  for (;;) {
    int mn = 0x7fffffff;
#pragma unroll
    for (int j = 0; j < PL; ++j) {
      int v = __hip_atomic_load(p0 + j * 16, __ATOMIC_RELAXED, __HIP_MEMORY_SCOPE_SYSTEM);
      mn = v < mn ? v : mn;
    }
    if (__all(mn >= need)) break;
    __builtin_amdgcn_s_sleep(1);
  }
  asm volatile("" ::: "memory");
}

// Persistent kernel: 256 WGs x 512 threads (8 waves), 1 WG/CU (LDS-bound).
// __launch_bounds__(512,1): LDS already caps occupancy at 1 WG/CU, so the
// register allocator gets the full 256-VGPR budget -> no scratch spill
// (R10's 128-cap spill was the 8.7ms / 8GB-HBM regression).
// Layer by XCD residue; rank 0..127; WG owns 8 h-cols. Weights in VGPRs.
// Wave roles: wv0-3 = epilogue + slack loads; wv4-7 = tight-chain consumers
// (poll+load overlapped with the epilogue). Per-epilogue-WAVE flags (wave
// drain -> lane0 fire). ONE raw s_barrier per step (zl triple-buffered).
//   L0: wv0,1 x (plain); wv4-7 h0 tight (ring0); wv0-3 backpressure poll.
//   L1: wv0-3 h0 slack (ring0); wv4-7 h1 tight (ring1). All h loads scoped.
__global__ __launch_bounds__(512, 1)
void lstm_v11(const ushort* __restrict__ xbf,
              const float* __restrict__ c0_in,
              const float* __restrict__ W0, const float* __restrict__ b0_,
              const float* __restrict__ W1, const float* __restrict__ b1_,
              ushort* __restrict__ ring0,   // [8][BNH] bf16, fragment layout
              ushort* __restrict__ ring1,   // [2][BNH] bf16, fragment layout
              int* __restrict__ flags,      // 1024 wave-flags x 16 ints
              float* __restrict__ out) {
  __shared__ float zl[3][8][32][36];        // triple-buffered z partials

  const int wg    = blockIdx.x;
  const int tid   = threadIdx.x;
  const int res   = wg & 7;
  const int layer = res >> 2;
  const int rank  = (wg >> 3) * 4 + (res & 3);
  const int j0    = rank * 8;
  const int K     = layer ? (2 * NH) : (NIN + NH);
  const float* W    = layer ? W1 : W0;
  const float* bias = layer ? b1_ : b0_;

  const int wv = tid >> 6, lane = tid & 63;
  const int kslot = layer ? wv : (wv < 2 ? wv : wv - 2);   // L0: wv2,3 idle
  const bool kact = layer || wv < 2 || wv >= 4;

  // ---- weight K-slice into registers (once) ----
  short8v wreg[8][2];
  if (kact) {
    const int wkbase = kslot * 256;
#pragma unroll
    for (int q = 0; q < 8; ++q)
#pragma unroll
      for (int nt = 0; nt < 2; ++nt) {
        int n  = nt * 16 + (lane & 15);
        int gr = (n >> 3) * NH + j0 + (n & 7);
        int k  = wkbase + q * 32 + (lane >> 4) * 8;
        const float* p = W + (size_t)gr * K + k;
        wreg[q][nt] = cvt8(*(const float4*)p, *(const float4*)(p + 4));
      }
  } else {
#pragma unroll
    for (int q = 0; q < 8; ++q) { wreg[q][0] = short8v{}; wreg[q][1] = short8v{}; }
  }

  // zero all 3 zl buffers for my wave slice
  for (int b3 = 0; b3 < 3; ++b3)
    for (int i = lane; i < 32 * 36; i += 64) (&zl[b3][wv][0][0])[i] = 0.f;

  // epilogue state (threads 0..255): thread -> (batch bb, col jj)
  const int bb = tid >> 3, jj = tid & 7;
  float c = 0.f, bg0 = 0.f, bg1 = 0.f, bg2 = 0.f, bg3 = 0.f;
  if (tid < 256) {
    bg0 = bias[0 * NH + j0 + jj];
    bg1 = bias[1 * NH + j0 + jj];
    bg2 = bias[2 * NH + j0 + jj];
    bg3 = bias[3 * NH + j0 + jj];
    c   = c0_in[layer * BNH + bb * NH + j0 + jj];
  }

  __syncthreads();

  for (int it = 0; it <= TSTEPS; ++it) {
    const bool gemm = (it < TSTEPS);
    short8v f[2][8];

    // ---- tight waves: poll own-layer wave-flags, issue scoped loads ----
    if (gemm && wv >= 4) {
      const int i = wv - 4;
      if (layer == 0) {
        wpoll<2>(flags, 128 * i, it, lane);               // L0 ranks [32i,32i+32)
        kload_b(ring0 + (size_t)(it & 7) * BNH + 8 * i * 1024, lane, f);
      } else {
        wpoll<2>(flags, 512 + 128 * i, it, lane);         // L1 ranks [32i,32i+32)
        kload_b(ring1 + (size_t)((it + 1) & 1) * BNH + 8 * i * 1024, lane, f);
      }
    }
    // ---- L0 epilogue waves: backpressure BEFORE the ring0 overwrite ----
    if (layer == 0 && wv < 4) {
      wpoll<2>(flags, 512 + 128 * wv, it - 6, lane);      // L1 done it-7 (+margin)
    }
    // ---- epilogue for step it-1 (waves 0-3) ----
    if (it >= 1 && tid < 256) {
      const int zb = (it + 2) % 3;                        // (it-1) mod 3
      float zg[4];
#pragma unroll
      for (int g = 0; g < 4; ++g) {
        float s = 0.f;
#pragma unroll
        for (int w = 0; w < 8; ++w) s += zl[zb][w][bb][g * 8 + jj];
        zg[g] = s;
      }
      float g1 = 1.f / (1.f + __expf(-(zg[0] + bg0)));
      float g2 = 1.f / (1.f + __expf(-(zg[1] + bg1)));
      float g3 = 1.f / (1.f + __expf(-(zg[2] + bg2)));
      float o  = tanhf(zg[3] + bg3);
      c = c * g1 + o * g2;
      float h = tanhf(c) * g3;
      unsigned short hb = f2bf(h);
      int so = swzx(bb, j0 + jj);
      if (layer == 0) {
        __hip_atomic_store(&ring0[(size_t)(it & 7) * BNH + so], hb,
                           __ATOMIC_RELAXED, __HIP_MEMORY_SCOPE_SYSTEM);
      } else {
        __hip_atomic_store(&ring1[(size_t)((it + 1) & 1) * BNH + so], hb,
                           __ATOMIC_RELAXED, __HIP_MEMORY_SCOPE_SYSTEM);
      }
      // wave-local drain (scoped store ack == visible at LLC), then wave flag
      asm volatile("s_waitcnt vmcnt(0)" ::: "memory");
      if (lane == 0) {
        __hip_atomic_store(&flags[(size_t)((layer * 128 + rank) * 4 + wv) * 16], it,
                           __ATOMIC_RELAXED, __HIP_MEMORY_SCOPE_SYSTEM);
      }
      if (layer == 1)
        out[(size_t)(it - 1) * BNH + bb * NH + j0 + jj] = h;   // plain, post-flag
    }
    // ---- slack loads (epilogue waves, after flag fire) ----
    if (gemm && wv < 4) {
      if (layer == 0) {
        if (wv < 2) kloadp(xbf + (size_t)it * 16384 + 8 * wv * 1024, lane, f);
      } else {
        wpoll<2>(flags, 128 * wv, it + 1, lane);          // L0 done step it
        kload_b(ring0 + (size_t)((it + 1) & 7) * BNH + 8 * wv * 1024, lane, f);
      }
    }
    // ---- compute + zl publish ----
    if (gemm && kact) {
      float4v acc[2][2] = {{{0,0,0,0},{0,0,0,0}},{{0,0,0,0},{0,0,0,0}}};
      kmfma(f, wreg, acc);
      const int zc = it % 3;
#pragma unroll
      for (int mt = 0; mt < 2; ++mt)
#pragma unroll
        for (int nt = 0; nt < 2; ++nt)
#pragma unroll
          for (int r = 0; r < 4; ++r)
            zl[zc][wv][mt * 16 + (lane >> 4) * 4 + r][nt * 16 + (lane & 15)] = acc[mt][nt][r];
    }
    // single barrier per step: LDS drained, global loads may stay in flight
    asm volatile("s_waitcnt lgkmcnt(0)" ::: "memory");
    __builtin_amdgcn_s_barrier();
    asm volatile("" ::: "memory");
  }
}

// prep: x -> bf16 fragment layout, ring init slots, zero flags, output tail
__global__ void prep(const float* __restrict__ x,
                     const float* __restrict__ h0_in, const float* __restrict__ c0_in,
                     ushort* __restrict__ xbf, ushort* __restrict__ ring0,
                     ushort* __restrict__ ring1, int* __restrict__ flags,
                     float* __restrict__ out) {
  int i = blockIdx.x * blockDim.x + threadIdx.x;   // 0 .. T*B*NIN-1
  {
    int t = i >> 14, rem = i & 16383;
    int b = rem >> 9, k = rem & 511;
    xbf[(size_t)t * 16384 + swzx(b, k)] = f2bf(x[i]);
  }
  if (i < BNH) {
    int b = i >> 10, j = i & 1023;
    int so = swzx(b, j);
    __hip_atomic_store(&ring0[so], f2bf(h0_in[i]),              // slot 0 = h0_{-1}
                       __ATOMIC_RELAXED, __HIP_MEMORY_SCOPE_SYSTEM);
    __hip_atomic_store(&ring1[BNH + so], f2bf(h0_in[BNH + i]),  // slot 1 = h1_{-1}
                       __ATOMIC_RELAXED, __HIP_MEMORY_SCOPE_SYSTEM);
  }
  if (i < 1024 * 16) {
    __hip_atomic_store(&flags[i], 0, __ATOMIC_RELAXED, __HIP_MEMORY_SCOPE_SYSTEM);
  }
  if (i < 2 * BNH) {
    const size_t TB = (size_t)TSTEPS * BNH;
    out[TB + i]           = h0_in[i];
    out[TB + 2 * BNH + i] = c0_in[i];
  }
}

extern "C" void kernel_launch(void* const* d_in, const int* in_sizes, int n_in,
                              void* d_out, int out_size, void* d_ws, size_t ws_size,
                              hipStream_t stream) {
  const float* x  = (const float*)d_in[0];
  const float* h0 = (const float*)d_in[1];
  const float* c0 = (const float*)d_in[2];
  const float* W0 = (const float*)d_in[3];
  const float* b0 = (const float*)d_in[4];
  const float* W1 = (const float*)d_in[5];
  const float* b1 = (const float*)d_in[6];
  float* out = (float*)d_out;

  ushort* xbf   = (ushort*)d_ws;                              // 16 MiB
  ushort* ring0 = (ushort*)((char*)d_ws + 16777216);          // 512 KiB
  ushort* ring1 = (ushort*)((char*)d_ws + 17301504);          // 128 KiB
  int*    flags = (int*)((char*)d_ws + 17432576);             // 64 KiB

  prep<<<dim3(32768), dim3(256), 0, stream>>>(x, h0, c0, xbf, ring0, ring1, flags, out);

  void* args[] = {(void*)&xbf, (void*)&c0, (void*)&W0, (void*)&b0, (void*)&W1,
                  (void*)&b1, (void*)&ring0, (void*)&ring1, (void*)&flags, (void*)&out};
  (void)hipLaunchCooperativeKernel((const void*)lstm_v11, dim3(256), dim3(512),
                                   args, 0, stream);
}

// Round 12
// 3844.041 us; speedup vs baseline: 2.2597x; 2.2576x over previous
//
#include <hip/hip_runtime.h>
#include <hip/hip_bf16.h>

#define TSTEPS 512
#define BATCH  32
#define NIN    512
#define NH     1024
#define BNH    (BATCH * NH)   // 32768

typedef __attribute__((ext_vector_type(8))) short  short8v;
typedef __attribute__((ext_vector_type(4))) float  float4v;
typedef unsigned long long ull;

__device__ __forceinline__ unsigned short f2bf(float f) {
  return __builtin_bit_cast(unsigned short, __float2bfloat16(f));
}
__device__ __forceinline__ float4v mfma16(short8v a, short8v b, float4v c) {
  return __builtin_amdgcn_mfma_f32_16x16x32_bf16(a, b, c, 0, 0, 0);
}

// bf16 fragment layout (R7/R8-verified): element (b,k) at
//   (k>>5)*1024 + (b>>4)*512 + (((b&15)|(((k>>3)&3)<<4))<<3) + (k&7)
// -> wave A-fragment: 16B at base + q*1024 + mt*512 + lane*8.
__device__ __forceinline__ int swzx(int b, int k) {
  return (k >> 5) * 1024 + (b >> 4) * 512 +
         (((b & 15) | (((k >> 3) & 3) << 4)) << 3) + (k & 7);
}

__device__ __forceinline__ short8v cvt8(float4 f0, float4 f1) {
  short8v r;
  r[0] = (short)f2bf(f0.x); r[1] = (short)f2bf(f0.y);
  r[2] = (short)f2bf(f0.z); r[3] = (short)f2bf(f0.w);
  r[4] = (short)f2bf(f1.x); r[5] = (short)f2bf(f1.y);
  r[6] = (short)f2bf(f1.z); r[7] = (short)f2bf(f1.w);
  return r;
}

// 16 fragments via COMPILER-MANAGED scoped 8B-pair loads (R7-proven safe).
__device__ __forceinline__ void kload_b(const ushort* __restrict__ base, int lane,
                                        short8v (&f)[2][8]) {
#pragma unroll
  for (int mt = 0; mt < 2; ++mt)
#pragma unroll
    for (int q = 0; q < 8; ++q) {
      const ull* p = (const ull*)(base + q * 1024 + mt * 512 + lane * 8);
      ull lo = __hip_atomic_load(p,     __ATOMIC_RELAXED, __HIP_MEMORY_SCOPE_SYSTEM);
      ull hi = __hip_atomic_load(p + 1, __ATOMIC_RELAXED, __HIP_MEMORY_SCOPE_SYSTEM);
      union { ull u[2]; short8v v; } cv;
      cv.u[0] = lo; cv.u[1] = hi;
      f[mt][q] = cv.v;
    }
}

// plain cached 16B loads (immutable xbf)
__device__ __forceinline__ void kloadp(const ushort* __restrict__ base, int lane,
                                       short8v (&f)[2][8]) {
#pragma unroll
  for (int mt = 0; mt < 2; ++mt)
#pragma unroll
    for (int q = 0; q < 8; ++q)
      f[mt][q] = *(const short8v*)(base + q * 1024 + mt * 512 + lane * 8);
}

__device__ __forceinline__ void kmfma(const short8v (&f)[2][8],
                                      const short8v (&w)[8][2],
                                      float4v (&acc)[2][2]) {
#pragma unroll
  for (int q = 0; q < 8; ++q)
#pragma unroll
    for (int mt = 0; mt < 2; ++mt) {
      acc[mt][0] = mfma16(f[mt][q], w[q][0], acc[mt][0]);
      acc[mt][1] = mfma16(f[mt][q], w[q][1], acc[mt][1]);
    }
}

// wave-parallel flag poll: 2 flag slots per lane (128 slots), all >= need
__device__ __forceinline__ void wpoll(const int* __restrict__ flags, int base,
                                      int need, int lane) {
  if (need <= 0) return;
  const int* p0 = &flags[(size_t)(base + lane * 2) * 16];
  for (;;) {
    int a = __hip_atomic_load(p0,      __ATOMIC_RELAXED, __HIP_MEMORY_SCOPE_SYSTEM);
    int b = __hip_atomic_load(p0 + 16, __ATOMIC_RELAXED, __HIP_MEMORY_SCOPE_SYSTEM);
    if (__all((a >= need) && (b >= need))) break;
    __builtin_amdgcn_s_sleep(1);
  }
  asm volatile("" ::: "memory");
}

// Persistent kernel: 256 WGs x 512 threads (8 waves), 1 WG/CU.
// Layer by XCD residue; rank 0..127; WG owns 8 h-cols. Weights in VGPRs.
// CONTAINED LIVENESS (R12 fix): every role branch does its own
// poll -> load -> mfma -> zl write, so fragment registers never live across
// the epilogue region (R10/R11's 64-VGPR f crossing branches caused the
// 8 GB/launch scratch spill at the backend's hard 128-VGPR budget).
// Slot convention: h_t -> ring slot (t+1) mod depth. Flag value v = epilogue
// of step v-1 complete (h_{v-1} visible at LLC).
// Per step: wv0-3 run epilogue(it-1) [zl-prev sum, gates, scoped h store,
// wave drain, per-wave flag], then their slack K-part; wv4-7 poll+load+mfma
// the tight K-part. One s_barrier per step; zl double-buffered, 36-padded.
__global__ __launch_bounds__(512, 1)
void lstm_v12(const ushort* __restrict__ xbf,
              const float* __restrict__ c0_in,
              const float* __restrict__ W0, const float* __restrict__ b0_,
              const float* __restrict__ W1, const float* __restrict__ b1_,
              ushort* __restrict__ ring0,   // [8][BNH] bf16, fragment layout
              ushort* __restrict__ ring1,   // [2][BNH] bf16, fragment layout
              int* __restrict__ flags,      // 1024 wave-flags x 16 ints (64B apart)
              float* __restrict__ out) {
  __shared__ float zl[2][8][32][36];        // double-buffered, padded z partials

  const int wg    = blockIdx.x;
  const int tid   = threadIdx.x;
  const int res   = wg & 7;
  const int layer = res >> 2;
  const int rank  = (wg >> 3) * 4 + (res & 3);
  const int j0    = rank * 8;
  const int K     = layer ? (2 * NH) : (NIN + NH);
  const float* W    = layer ? W1 : W0;
  const float* bias = layer ? b1_ : b0_;

  const int wv = tid >> 6, lane = tid & 63;
  // L0 K=1536: wv0,1 = x slices (k 0-511); wv4-7 = h0 slices (k 512-1535);
  // wv2,3 compute-idle. L1 K=2048: wv0-3 = h0; wv4-7 = h1.
  const int kslot = layer ? wv : (wv < 2 ? wv : wv - 2);
  const bool kact = layer || wv < 2 || wv >= 4;

  // ---- weight K-slice into registers (once) ----
  short8v wreg[8][2];
  if (kact) {
    const int wkbase = kslot * 256;
#pragma unroll
    for (int q = 0; q < 8; ++q)
#pragma unroll
      for (int nt = 0; nt < 2; ++nt) {
        int n  = nt * 16 + (lane & 15);
        int gr = (n >> 3) * NH + j0 + (n & 7);
        int k  = wkbase + q * 32 + (lane >> 4) * 8;
        const float* p = W + (size_t)gr * K + k;
        wreg[q][nt] = cvt8(*(const float4*)p, *(const float4*)(p + 4));
      }
  } else {
#pragma unroll
    for (int q = 0; q < 8; ++q) { wreg[q][0] = short8v{}; wreg[q][1] = short8v{}; }
  }

  // zero both zl buffers for my wave slice (L0 wv2,3 stay zero forever)
  for (int b2 = 0; b2 < 2; ++b2)
    for (int i = lane; i < 32 * 36; i += 64) (&zl[b2][wv][0][0])[i] = 0.f;

  // epilogue state (threads 0..255): thread -> (batch bb, col jj)
  const int bb = tid >> 3, jj = tid & 7;
  float c = 0.f, bg0 = 0.f, bg1 = 0.f, bg2 = 0.f, bg3 = 0.f;
  if (tid < 256) {
    bg0 = bias[0 * NH + j0 + jj];
    bg1 = bias[1 * NH + j0 + jj];
    bg2 = bias[2 * NH + j0 + jj];
    bg3 = bias[3 * NH + j0 + jj];
    c   = c0_in[layer * BNH + bb * NH + j0 + jj];
  }

  __syncthreads();

  for (int it = 0; it <= TSTEPS; ++it) {
    const bool gemm = (it < TSTEPS);
    const int zc = it & 1;

    if (wv < 4) {
      // ---- epilogue(it-1): gates, state, publish h, wave-local flag ----
      if (it >= 1) {
        const int zp = (it - 1) & 1;
        float zg[4];
#pragma unroll
        for (int g = 0; g < 4; ++g) {
          float s = 0.f;
#pragma unroll
          for (int w = 0; w < 8; ++w) s += zl[zp][w][bb][g * 8 + jj];
          zg[g] = s;
        }
        float g1 = 1.f / (1.f + __expf(-(zg[0] + bg0)));
        float g2 = 1.f / (1.f + __expf(-(zg[1] + bg1)));
        float g3 = 1.f / (1.f + __expf(-(zg[2] + bg2)));
        float o  = tanhf(zg[3] + bg3);
        c = c * g1 + o * g2;
        float h = tanhf(c) * g3;
        unsigned short hb = f2bf(h);
        int so = swzx(bb, j0 + jj);
        if (layer == 0) {
          __hip_atomic_store(&ring0[(size_t)(it & 7) * BNH + so], hb,
                             __ATOMIC_RELAXED, __HIP_MEMORY_SCOPE_SYSTEM);
        } else {
          __hip_atomic_store(&ring1[(size_t)(it & 1) * BNH + so], hb,
                             __ATOMIC_RELAXED, __HIP_MEMORY_SCOPE_SYSTEM);
        }
        asm volatile("s_waitcnt vmcnt(0)" ::: "memory");   // wave-local drain
        if (lane == 0) {
          __hip_atomic_store(&flags[(size_t)((layer * 128 + rank) * 4 + wv) * 16], it,
                             __ATOMIC_RELAXED, __HIP_MEMORY_SCOPE_SYSTEM);
        }
        if (layer == 1)
          out[(size_t)(it - 1) * BNH + bb * NH + j0 + jj] = h;  // plain, post-flag
      }
      // ---- slack K-part for step it (contained poll->load->mfma->zl) ----
      if (gemm) {
        if (layer == 0) {
          // quartered backpressure: barrier(it-1) certified all >= it-7,
          // overwrite at epilogue(it) needs >= it-8 -> margin-safe (R11 proof)
          wpoll(flags, 512 + 128 * wv, it - 6, lane);
          if (wv < 2) {
            short8v f[2][8];
            kloadp(xbf + (size_t)it * 16384 + wv * 8 * 1024, lane, f);
            float4v acc[2][2] = {{{0,0,0,0},{0,0,0,0}},{{0,0,0,0},{0,0,0,0}}};
            kmfma(f, wreg, acc);
#pragma unroll
            for (int mt = 0; mt < 2; ++mt)
#pragma unroll
              for (int nt = 0; nt < 2; ++nt)
#pragma unroll
                for (int r = 0; r < 4; ++r)
                  zl[zc][wv][mt * 16 + (lane >> 4) * 4 + r][nt * 16 + (lane & 15)] = acc[mt][nt][r];
          }
        } else {
          wpoll(flags, 128 * wv, it + 1, lane);          // h0_it ready (slack)
          short8v f[2][8];
          kload_b(ring0 + (size_t)((it + 1) & 7) * BNH + wv * 8 * 1024, lane, f);
          float4v acc[2][2] = {{{0,0,0,0},{0,0,0,0}},{{0,0,0,0},{0,0,0,0}}};
          kmfma(f, wreg, acc);
#pragma unroll
          for (int mt = 0; mt < 2; ++mt)
#pragma unroll
            for (int nt = 0; nt < 2; ++nt)
#pragma unroll
              for (int r = 0; r < 4; ++r)
                zl[zc][wv][mt * 16 + (lane >> 4) * 4 + r][nt * 16 + (lane & 15)] = acc[mt][nt][r];
        }
      }
    } else if (gemm) {
      // ---- tight K-part for step it ----
      short8v f[2][8];
      if (layer == 0) {
        wpoll(flags, 128 * (wv - 4), it, lane);          // h0_{it-1} ready
        kload_b(ring0 + (size_t)(it & 7) * BNH + (wv - 4) * 8 * 1024, lane, f);
      } else {
        wpoll(flags, 512 + 128 * (wv - 4), it, lane);    // h1_{it-1} ready
        kload_b(ring1 + (size_t)(it & 1) * BNH + (wv - 4) * 8 * 1024, lane, f);
      }
      float4v acc[2][2] = {{{0,0,0,0},{0,0,0,0}},{{0,0,0,0},{0,0,0,0}}};
      kmfma(f, wreg, acc);
#pragma unroll
      for (int mt = 0; mt < 2; ++mt)
#pragma unroll
        for (int nt = 0; nt < 2; ++nt)
#pragma unroll
          for (int r = 0; r < 4; ++r)
            zl[zc][wv][mt * 16 + (lane >> 4) * 4 + r][nt * 16 + (lane & 15)] = acc[mt][nt][r];
    }

    // one barrier per step (zl double-buffer makes it sufficient)
    asm volatile("s_waitcnt lgkmcnt(0)" ::: "memory");
    __builtin_amdgcn_s_barrier();
    asm volatile("" ::: "memory");
  }
}

// prep: x -> bf16 fragment layout, ring init (slot 0 = h_{-1} for BOTH rings
// under the h_t -> slot (t+1) convention), zero flags, output tail.
__global__ void prep(const float* __restrict__ x,
                     const float* __restrict__ h0_in, const float* __restrict__ c0_in,
                     ushort* __restrict__ xbf, ushort* __restrict__ ring0,
                     ushort* __restrict__ ring1, int* __restrict__ flags,
                     float* __restrict__ out) {
  int i = blockIdx.x * blockDim.x + threadIdx.x;   // 0 .. T*B*NIN-1
  {
    int t = i >> 14, rem = i & 16383;
    int b = rem >> 9, k = rem & 511;
    xbf[(size_t)t * 16384 + swzx(b, k)] = f2bf(x[i]);
  }
  if (i < BNH) {
    int b = i >> 10, j = i & 1023;
    int so = swzx(b, j);
    __hip_atomic_store(&ring0[so], f2bf(h0_in[i]),          // slot 0 = h0_{-1}
                       __ATOMIC_RELAXED, __HIP_MEMORY_SCOPE_SYSTEM);
    __hip_atomic_store(&ring1[so], f2bf(h0_in[BNH + i]),    // slot 0 = h1_{-1}
                       __ATOMIC_RELAXED, __HIP_MEMORY_SCOPE_SYSTEM);
  }
  if (i < 1024 * 16) {
    __hip_atomic_store(&flags[i], 0, __ATOMIC_RELAXED, __HIP_MEMORY_SCOPE_SYSTEM);
  }
  if (i < 2 * BNH) {
    const size_t TB = (size_t)TSTEPS * BNH;
    out[TB + i]           = h0_in[i];
    out[TB + 2 * BNH + i] = c0_in[i];
  }
}

extern "C" void kernel_launch(void* const* d_in, const int* in_sizes, int n_in,
                              void* d_out, int out_size, void* d_ws, size_t ws_size,
                              hipStream_t stream) {
  const float* x  = (const float*)d_in[0];
  const float* h0 = (const float*)d_in[1];
  const float* c0 = (const float*)d_in[2];
  const float* W0 = (const float*)d_in[3];
  const float* b0 = (const float*)d_in[4];
  const float* W1 = (const float*)d_in[5];
  const float* b1 = (const float*)d_in[6];
  float* out = (float*)d_out;

  ushort* xbf   = (ushort*)d_ws;                              // 16 MiB
  ushort* ring0 = (ushort*)((char*)d_ws + 16777216);          // 512 KiB
  ushort* ring1 = (ushort*)((char*)d_ws + 17301504);          // 128 KiB
  int*    flags = (int*)((char*)d_ws + 17432576);             // 64 KiB

  prep<<<dim3(32768), dim3(256), 0, stream>>>(x, h0, c0, xbf, ring0, ring1, flags, out);

  void* args[] = {(void*)&xbf, (void*)&c0, (void*)&W0, (void*)&b0, (void*)&W1,
                  (void*)&b1, (void*)&ring0, (void*)&ring1, (void*)&flags, (void*)&out};
  (void)hipLaunchCooperativeKernel((const void*)lstm_v12, dim3(256), dim3(512),
                                   args, 0, stream);
}

// Round 14
// 2489.232 us; speedup vs baseline: 3.4896x; 1.5443x over previous
//
#include <hip/hip_runtime.h>
#include <hip/hip_bf16.h>

#define TSTEPS 512
#define BATCH  32
#define NIN    512
#define NH     1024
#define BNH    (BATCH * NH)   // 32768

typedef __attribute__((ext_vector_type(8))) short  short8v;
typedef __attribute__((ext_vector_type(4))) float  float4v;
typedef unsigned long long ull;

__device__ __forceinline__ unsigned short f2bf(float f) {
  return __builtin_bit_cast(unsigned short, __float2bfloat16(f));
}
__device__ __forceinline__ float4v mfma16(short8v a, short8v b, float4v c) {
  return __builtin_amdgcn_mfma_f32_16x16x32_bf16(a, b, c, 0, 0, 0);
}

// h state swizzle (8B-atomic-pair layout, R7-proven): element (b,k) at
//   (k>>5)*1024 + (b>>4)*512 + ((k>>2)&1)*256 + ((b&15)|(((k>>3)&3)<<4))*4 + (k&3)
__device__ __forceinline__ int swzh(int b, int k) {
  return (k >> 5) * 1024 + (b >> 4) * 512 + ((k >> 2) & 1) * 256 +
         (((b & 15) | (((k >> 3) & 3) << 4)) << 2) + (k & 3);
}
// x bf16 swizzle (plain 16B layout)
__device__ __forceinline__ int swzx(int b, int k) {
  return (k >> 5) * 1024 + (b >> 4) * 512 +
         (((b & 15) | (((k >> 3) & 3) << 4)) << 3) + (k & 7);
}

// 8-k-iter partial GEMM: A from memory (X16: plain 16B bf16; else scoped 8B
// pairs via LLC), B from registers. acc[mt][nt] over 2 M-tiles x 2 N-tiles.
template<bool X16>
__device__ __forceinline__ void kpart8(const ushort* __restrict__ base, int kgb,
                                       int lane, const short8v (&wreg)[8][2],
                                       float4v (&acc)[2][2]) {
  if constexpr (X16) {
    short8v f[2][8];
#pragma unroll
    for (int mt = 0; mt < 2; ++mt)
#pragma unroll
      for (int q = 0; q < 8; ++q)
        f[mt][q] = *(const short8v*)(base + (size_t)(kgb + q) * 1024 + mt * 512 + lane * 8);
#pragma unroll
    for (int q = 0; q < 8; ++q)
#pragma unroll
      for (int mt = 0; mt < 2; ++mt) {
        acc[mt][0] = mfma16(f[mt][q], wreg[q][0], acc[mt][0]);
        acc[mt][1] = mfma16(f[mt][q], wreg[q][1], acc[mt][1]);
      }
  } else {
    ull lo[2][8], hi[2][8];
#pragma unroll
    for (int mt = 0; mt < 2; ++mt)
#pragma unroll
      for (int q = 0; q < 8; ++q) {
        const ull* p = (const ull*)(base + (size_t)(kgb + q) * 1024 + mt * 512 + lane * 4);
        lo[mt][q] = __hip_atomic_load(p,      __ATOMIC_RELAXED, __HIP_MEMORY_SCOPE_SYSTEM);
        hi[mt][q] = __hip_atomic_load(p + 64, __ATOMIC_RELAXED, __HIP_MEMORY_SCOPE_SYSTEM);
      }
#pragma unroll
    for (int q = 0; q < 8; ++q)
#pragma unroll
      for (int mt = 0; mt < 2; ++mt) {
        union { ull u[2]; short8v v; } cv;
        cv.u[0] = lo[mt][q]; cv.u[1] = hi[mt][q];
        acc[mt][0] = mfma16(cv.v, wreg[q][0], acc[mt][0]);
        acc[mt][1] = mfma16(cv.v, wreg[q][1], acc[mt][1]);
      }
  }
}

// per-wave flag poll (R7-proven, no sleep): lanes share cnt flags, spin
__device__ __forceinline__ void wave_poll(const int* __restrict__ flags,
                                          int base, int cnt, int need, int lane) {
  if (need <= 0) return;
  const int* f = flags + (size_t)(base + (lane & (cnt - 1))) * 16;
  while (!__all(__hip_atomic_load(f, __ATOMIC_RELAXED, __HIP_MEMORY_SCOPE_SYSTEM) >= need)) {}
  asm volatile("" ::: "memory");
}

// Persistent kernel: 256 WGs x 512 threads (8 waves, 2/SIMD), 1 WG/CU.
// EXACT R7 structure (proven 2.78 ms) with exactly two verified fixes:
//   (1) zl padded [32][36] (R12-verified: kills the diagonal read conflict)
//   (2) L1 out-store moved after the flag publication (off the critical path)
// R14 fix: prep zeroes the FULL stride-16 flag range (R13 zeroed only 1/4 ->
// poisoned flags after the harness's 0xAA ws-poison -> replay races).
__global__ __launch_bounds__(512, 2)
void lstm_r14(const float* __restrict__ c0_in,
              const float* __restrict__ W0, const float* __restrict__ b0_,
              const float* __restrict__ W1, const float* __restrict__ b1_,
              const ushort* __restrict__ xbf,
              ushort* __restrict__ ring0,   // [8][BNH] bf16, swizzled
              ushort* __restrict__ ring1,   // [2][BNH] bf16, swizzled
              int* __restrict__ flags,      // 256 producers, stride 16 ints
              float* __restrict__ out) {
  __shared__ float zl[8][32][36];          // per-wave z partials, 36-pad

  const int wg    = blockIdx.x;
  const int tid   = threadIdx.x;
  const int res   = wg & 7;
  const int layer = res >> 2;
  const int rank  = (wg >> 3) * 4 + (res & 3);
  const int j0    = rank * 8;
  const int K     = layer ? (2 * NH) : (NIN + NH);
  const float* W    = layer ? W1 : W0;
  const float* bias = layer ? b1_ : b0_;

  const int wv = tid >> 6, lane = tid & 63;
  const bool kactive = layer ? true : (wv < 6);

  // ---- preload this wave's weight K-slice into registers (once) ----
  short8v wreg[8][2];
  if (kactive) {
    const int wkbase = wv * 256;
#pragma unroll
    for (int q = 0; q < 8; ++q)
#pragma unroll
      for (int nt = 0; nt < 2; ++nt) {
        int n  = nt * 16 + (lane & 15);
        int gr = (n >> 3) * NH + j0 + (n & 7);
        int k  = wkbase + q * 32 + (lane >> 4) * 8;
        const float* p = W + (size_t)gr * K + k;
        float4 f0 = *(const float4*)p;
        float4 f1 = *(const float4*)(p + 4);
        short8v r;
        r[0] = (short)f2bf(f0.x); r[1] = (short)f2bf(f0.y);
        r[2] = (short)f2bf(f0.z); r[3] = (short)f2bf(f0.w);
        r[4] = (short)f2bf(f1.x); r[5] = (short)f2bf(f1.y);
        r[6] = (short)f2bf(f1.z); r[7] = (short)f2bf(f1.w);
        wreg[q][nt] = r;
      }
  } else {
#pragma unroll
    for (int q = 0; q < 8; ++q) { wreg[q][0] = short8v{}; wreg[q][1] = short8v{}; }
  }

  // zero my z slice (idle L0 waves 6,7 leave theirs zero forever)
  for (int i = lane; i < 32 * 36; i += 64) (&zl[wv][0][0])[i] = 0.f;

  // epilogue state (threads 0..255): thread -> (batch bb, col jj)
  const int bb = tid >> 3, jj = tid & 7;
  float c = 0.f, bg0 = 0.f, bg1 = 0.f, bg2 = 0.f, bg3 = 0.f;
  if (tid < 256) {
    bg0 = bias[0 * NH + j0 + jj];
    bg1 = bias[1 * NH + j0 + jj];
    bg2 = bias[2 * NH + j0 + jj];
    bg3 = bias[3 * NH + j0 + jj];
    c   = c0_in[layer * BNH + bb * NH + j0 + jj];
  }

  __syncthreads();

  for (int it = 0; it < TSTEPS; ++it) {
    float4v acc[2][2] = {{{0,0,0,0},{0,0,0,0}},{{0,0,0,0},{0,0,0,0}}};

    if (layer == 0) {
      if (wv < 2) {
        kpart8<true>(xbf + (size_t)it * 16384, 8 * wv, lane, wreg, acc);
      } else if (wv < 6) {
        wave_poll(flags, 32 * (wv - 2), 32, it, lane);              // own layer
        kpart8<false>(ring0 + (size_t)(it & 7) * BNH, 8 * (wv - 2), lane, wreg, acc);
      } else {
        wave_poll(flags, 128 + 64 * (wv - 6), 64, it - 6, lane);    // backpressure
      }
    } else {
      if (wv < 4) {
        wave_poll(flags, 32 * wv, 32, it + 1, lane);                // L0 done step it
        kpart8<false>(ring0 + (size_t)((it + 1) & 7) * BNH, 8 * wv, lane, wreg, acc);
      } else {
        wave_poll(flags, 128 + 32 * (wv - 4), 32, it, lane);        // own layer
        kpart8<false>(ring1 + (size_t)((it + 1) & 1) * BNH, 8 * (wv - 4), lane, wreg, acc);
      }
    }

    if (kactive) {
#pragma unroll
      for (int mt = 0; mt < 2; ++mt)
#pragma unroll
        for (int nt = 0; nt < 2; ++nt)
#pragma unroll
          for (int r = 0; r < 4; ++r)
            zl[wv][mt * 16 + (lane >> 4) * 4 + r][nt * 16 + (lane & 15)] = acc[mt][nt][r];
    }
    __syncthreads();

    float hval = 0.f;
    if (tid < 256) {
      float zg[4];
#pragma unroll
      for (int g = 0; g < 4; ++g) {
        float s = 0.f;
#pragma unroll
        for (int w = 0; w < 8; ++w) s += zl[w][bb][g * 8 + jj];
        zg[g] = s;
      }
      float g1 = 1.f / (1.f + __expf(-(zg[0] + bg0)));
      float g2 = 1.f / (1.f + __expf(-(zg[1] + bg1)));
      float g3 = 1.f / (1.f + __expf(-(zg[2] + bg2)));
      float o  = tanhf(zg[3] + bg3);
      c = c * g1 + o * g2;
      hval = tanhf(c) * g3;
      unsigned short hb = f2bf(hval);
      int so = swzh(bb, j0 + jj);
      if (layer == 0) {
        __hip_atomic_store(&ring0[(size_t)((it + 1) & 7) * BNH + so], hb,
                           __ATOMIC_RELAXED, __HIP_MEMORY_SCOPE_SYSTEM);
      } else {
        __hip_atomic_store(&ring1[(size_t)(it & 1) * BNH + so], hb,
                           __ATOMIC_RELAXED, __HIP_MEMORY_SCOPE_SYSTEM);
      }
    }
    asm volatile("s_waitcnt vmcnt(0)" ::: "memory");   // drain scoped stores
    __syncthreads();
    if (tid == 0) {
      __hip_atomic_store(&flags[(size_t)(layer * 128 + rank) * 16], it + 1,
                         __ATOMIC_RELAXED, __HIP_MEMORY_SCOPE_SYSTEM);
    }
    // out store AFTER the flag: never read on-device, off the critical path
    if (layer == 1 && tid < 256)
      out[(size_t)it * BNH + bb * NH + j0 + jj] = hval;
  }
}

// prep: convert x -> bf16 in fragment order, init ring slots (swizzled),
// zero ALL 4096 flag ints (stride-16 x 256 producers -- R14 fix), copy the
// (h0,c0) passthrough tail of the output.
__global__ void prep(const float* __restrict__ x,
                     const float* __restrict__ h0_in, const float* __restrict__ c0_in,
                     ushort* __restrict__ xbf, ushort* __restrict__ ring0,
                     ushort* __restrict__ ring1, int* __restrict__ flags,
                     float* __restrict__ out) {
  int i = blockIdx.x * blockDim.x + threadIdx.x;   // 0 .. T*B*NIN-1
  {
    int t = i >> 14, rem = i & 16383;
    int b = rem >> 9, k = rem & 511;
    xbf[(size_t)t * 16384 + swzx(b, k)] = f2bf(x[i]);
  }
  if (i < BNH) {
    int b = i >> 10, j = i & 1023;
    int so = swzh(b, j);
    __hip_atomic_store(&ring0[so], f2bf(h0_in[i]),                 // h0_{-1}, slot 0
                       __ATOMIC_RELAXED, __HIP_MEMORY_SCOPE_SYSTEM);
    __hip_atomic_store(&ring1[BNH + so], f2bf(h0_in[BNH + i]),     // h1_{-1}, slot 1
                       __ATOMIC_RELAXED, __HIP_MEMORY_SCOPE_SYSTEM);
  }
  if (i < 4096) {   // FULL stride-16 flag range (256 producers x 16 ints)
    __hip_atomic_store(&flags[i], 0, __ATOMIC_RELAXED, __HIP_MEMORY_SCOPE_SYSTEM);
  }
  if (i < 2 * BNH) {
    const size_t TB = (size_t)TSTEPS * BNH;
    out[TB + i]           = h0_in[i];
    out[TB + 2 * BNH + i] = c0_in[i];
  }
}

extern "C" void kernel_launch(void* const* d_in, const int* in_sizes, int n_in,
                              void* d_out, int out_size, void* d_ws, size_t ws_size,
                              hipStream_t stream) {
  const float* x  = (const float*)d_in[0];
  const float* h0 = (const float*)d_in[1];
  const float* c0 = (const float*)d_in[2];
  const float* W0 = (const float*)d_in[3];
  const float* b0 = (const float*)d_in[4];
  const float* W1 = (const float*)d_in[5];
  const float* b1 = (const float*)d_in[6];
  float* out = (float*)d_out;

  ushort* xbf   = (ushort*)d_ws;                              // 16 MiB
  ushort* ring0 = (ushort*)((char*)d_ws + 16777216);          // 512 KiB
  ushort* ring1 = (ushort*)((char*)d_ws + 17301504);          // 128 KiB
  int*    flags = (int*)((char*)d_ws + 17432576);             // 16 KiB

  prep<<<dim3(32768), dim3(256), 0, stream>>>(x, h0, c0, xbf, ring0, ring1, flags, out);

  void* args[] = {(void*)&c0, (void*)&W0, (void*)&b0, (void*)&W1, (void*)&b1,
                  (void*)&xbf, (void*)&ring0, (void*)&ring1, (void*)&flags, (void*)&out};
  (void)hipLaunchCooperativeKernel((const void*)lstm_r14, dim3(256), dim3(512),
                                   args, 0, stream);
}